// Round 4
// baseline (442.633 us; speedup 1.0000x reference)
//
#include <hip/hip_runtime.h>

// SST input layer: window partition + per-window drop + flat2win re-indexing.
// Static config: WIN=12, GRID=468, BATCH=4, SHIFTS=((0,0),(6,6)), MAX_WIN_Y=40,
//   window ids in [0, 6400). DROP_INFO: cnt<30 -> lvl0,t30 ; cnt<60 -> lvl1,t60 ;
//   cnt<100000 -> lvl2,t100.
//
// Structure (5 stream-ordered dispatches):
//   K0 zero     : cnt0,cnt1,keptC0,dropCnt,roleCtr,doneCtr (19203 ints)
//   A  copyscat : unconditional NT feature copy (BW-bound blocks) FUSED with
//                 winscat (atomic-bound blocks) -> copy hides logic latency.
//                 Copy-early is valid: dropped rows are zeroed in D (drops
//                 are statistically zero: need window count>100 at mean 49).
//   B  rank0    : wave/window shfl rank -> keep0, rk0 (optimistic),
//                 fused shift-1 hist+scatter
//   C  rank1    : wave/window shfl rank -> keepF, rk1, keptC1 (closed form),
//                 keptC0 atomics, droplist of shift-1-dropped survivors
//   D  fixfinal : ticket-role fusion — first 2 arriving blocks: conti scans;
//                 next FIXB: droplist rk0 fixup; rest: per-voxel scalar
//                 outputs + zero dropped feat rows. Arrival-ordered tickets
//                 (atomicAdd) make producers always-resident -> deadlock-free;
//                 consumers spin on release/acquire done-counter (~2-3us).
//
// Verified algebra (R1-R3 all passed, absmax=0):
//   * keep0 kept set is an index-prefix per shift-0 window => rank-among-keep0
//     == rank-among-all.
//   * shift-1 kept set is an index-prefix of survivors => rank-among-kept ==
//     rank, keptC1 = min(k, target).
//   * rk0 = r - #{smaller-index keep0-members dropped by shift-1} (droplist).
// Garbage-safety: keepF written for every keep0-survivor; consumers gate with
// (keep0 && keepF).

#define NWIN 6400
#define CAP 128    // per-window segment cap; stat max count ~80 (11 sigma)
#define FIXB 30    // droplist-fixup producer blocks in D

typedef float f4 __attribute__((ext_vector_type(4)));

__device__ __forceinline__ int targ_of(int k) {
    return (k < 30) ? 30 : (k < 60) ? 60 : (k < 100000) ? 100 : 0;
}
__device__ __forceinline__ int lvl_of(int k) {
    return (k < 30) ? 0 : (k < 60) ? 1 : (k < 100000) ? 2 : -1;
}

// ---- K0: zero header (cnt0,cnt1,keptC0,dropCnt,roleCtr,doneCtr) ----
__global__ void k_zero(int* __restrict__ z) {
    int i = blockIdx.x * 256 + threadIdx.x;
    if (i < 3 * NWIN + 3) z[i] = 0;
}

// ---- A: unconditional NT feature copy + winscat, one grid ----
__global__ void __launch_bounds__(256) k_copyscat(
    const int4* __restrict__ c4, int n,
    int* __restrict__ w0a, int* __restrict__ w1a,
    int* __restrict__ cnt0, int* __restrict__ seg0,
    const f4* __restrict__ feat, f4* __restrict__ out, int fb) {
    int b = blockIdx.x;
    if (b < fb) {                                     // feature copy blocks
        int gid = b * 256 + threadIdx.x;
        if (gid < n * 32) {                           // 32 float4 per row
            f4 v = __builtin_nontemporal_load(&feat[gid]);
            __builtin_nontemporal_store(v, &out[gid]);
        }
        return;
    }
    int i = (b - fb) * 256 + threadIdx.x;             // winscat blocks
    if (i >= n) return;
    int4 c = c4[i];                                   // [b, z, y, x]
    int w0 = c.x * 1600 + (c.w / 12) * 40 + (c.z / 12);
    int w1 = c.x * 1600 + ((c.w + 6) / 12) * 40 + ((c.z + 6) / 12);
    w0a[i] = w0;
    w1a[i] = w1;
    int p = atomicAdd(&cnt0[w0], 1);
    if (p < CAP) seg0[w0 * CAP + p] = i;              // overflow -> serial path
}

// ---- B: shift-0 rank/keep + optimistic rk0 + fused shift-1 hist+scatter ----
__global__ void __launch_bounds__(256) k_rank0(
    const int* __restrict__ cnt0, const int* __restrict__ seg0,
    const int* __restrict__ w0a, const int* __restrict__ w1a, int n,
    int* __restrict__ keep0, int* __restrict__ rk0,
    int* __restrict__ cnt1, int* __restrict__ seg1) {
    int w = blockIdx.x * 4 + (threadIdx.x >> 6);
    int lane = threadIdx.x & 63;
    int k = cnt0[w];
    if (k == 0) return;
    int target = targ_of(k);
    const int* s = seg0 + w * CAP;
    if (k <= 64) {
        int v = (lane < k) ? s[lane] : 0x7FFFFFFF;
        int r = 0;
        for (int j = 0; j < k; j++) { int b = __shfl(v, j, 64); r += (b < v) ? 1 : 0; }
        if (lane < k) {
            int kp = (r < target) ? 1 : 0;
            keep0[v] = kp;
            if (kp) {
                rk0[v] = r;                           // rank among keep0 == r
                int w1 = w1a[v];
                int p = atomicAdd(&cnt1[w1], 1);
                if (p < CAP) seg1[w1 * CAP + p] = v;
            }
        }
    } else if (k <= CAP) {
        int k2 = k - 64;
        int v0 = s[lane];
        int v1 = (lane < k2) ? s[64 + lane] : 0x7FFFFFFF;
        int r0 = 0, r1 = 0;
        for (int j = 0; j < 64; j++) { int b = __shfl(v0, j, 64); r0 += (b < v0); r1 += (b < v1); }
        for (int j = 0; j < k2; j++) { int b = __shfl(v1, j, 64); r0 += (b < v0); r1 += (b < v1); }
        {
            int kp = (r0 < target) ? 1 : 0;
            keep0[v0] = kp;
            if (kp) {
                rk0[v0] = r0;
                int w1 = w1a[v0]; int p = atomicAdd(&cnt1[w1], 1);
                if (p < CAP) seg1[w1 * CAP + p] = v0;
            }
        }
        if (lane < k2) {
            int kp = (r1 < target) ? 1 : 0;
            keep0[v1] = kp;
            if (kp) {
                rk0[v1] = r1;
                int w1 = w1a[v1]; int p = atomicAdd(&cnt1[w1], 1);
                if (p < CAP) seg1[w1 * CAP + p] = v1;
            }
        }
    } else {
        // correctness fallback (statistically never): serial in-order scan
        if (lane == 0) {
            int c = 0;
            for (int i = 0; i < n; i++) {
                if (w0a[i] == w) {
                    int kp = (c < target) ? 1 : 0;
                    keep0[i] = kp;
                    if (kp) {
                        rk0[i] = c;
                        int w1 = w1a[i]; int p = atomicAdd(&cnt1[w1], 1);
                        if (p < CAP) seg1[w1 * CAP + p] = i;
                    }
                    c++;
                }
            }
        }
    }
}

// ---- C: shift-1 rank -> keepF, rk1, keptC1, keptC0 atomics, droplist ----
__global__ void __launch_bounds__(256) k_rank1(
    const int* __restrict__ cnt1, const int* __restrict__ seg1,
    const int* __restrict__ w0a, const int* __restrict__ w1a,
    const int* __restrict__ keep0, int n,
    int* __restrict__ keepF, int* __restrict__ rk1,
    int* __restrict__ keptC1, int* __restrict__ keptC0,
    int* __restrict__ dropCnt, int* __restrict__ droplist) {
    int w = blockIdx.x * 4 + (threadIdx.x >> 6);
    int lane = threadIdx.x & 63;
    int k = cnt1[w];
    int target = targ_of(k);
    if (lane == 0) keptC1[w] = (k < target) ? k : target;   // prefix property
    if (k == 0) return;
    const int* s = seg1 + w * CAP;
    if (k <= 64) {
        int v = (lane < k) ? s[lane] : 0x7FFFFFFF;
        int r = 0;
        for (int j = 0; j < k; j++) { int b = __shfl(v, j, 64); r += (b < v) ? 1 : 0; }
        if (lane < k) {
            int kp = (r < target) ? 1 : 0;
            keepF[v] = kp;
            if (kp) { rk1[v] = r; atomicAdd(&keptC0[w0a[v]], 1); }
            else    { int d = atomicAdd(dropCnt, 1); droplist[d] = v; }
        }
    } else if (k <= CAP) {
        int k2 = k - 64;
        int v0 = s[lane];
        int v1 = (lane < k2) ? s[64 + lane] : 0x7FFFFFFF;
        int r0 = 0, r1 = 0;
        for (int j = 0; j < 64; j++) { int b = __shfl(v0, j, 64); r0 += (b < v0); r1 += (b < v1); }
        for (int j = 0; j < k2; j++) { int b = __shfl(v1, j, 64); r0 += (b < v0); r1 += (b < v1); }
        {
            int kp = (r0 < target) ? 1 : 0;
            keepF[v0] = kp;
            if (kp) { rk1[v0] = r0; atomicAdd(&keptC0[w0a[v0]], 1); }
            else    { int d = atomicAdd(dropCnt, 1); droplist[d] = v0; }
        }
        if (lane < k2) {
            int kp = (r1 < target) ? 1 : 0;
            keepF[v1] = kp;
            if (kp) { rk1[v1] = r1; atomicAdd(&keptC0[w0a[v1]], 1); }
            else    { int d = atomicAdd(dropCnt, 1); droplist[d] = v1; }
        }
    } else {
        if (lane == 0) {
            int c = 0;
            for (int i = 0; i < n; i++) {
                if (w1a[i] == w && keep0[i]) {
                    int kp = (c < target) ? 1 : 0;
                    keepF[i] = kp;
                    if (kp) { rk1[i] = c; atomicAdd(&keptC0[w0a[i]], 1); }
                    else    { int d = atomicAdd(dropCnt, 1); droplist[d] = i; }
                    c++;
                }
            }
        }
    }
}

// ---- D: conti scans + droplist fixup + scalar outputs (ticket roles) ----
__device__ __forceinline__ void conti_scan(
    const int* __restrict__ cnt, const int* __restrict__ keptC,
    int* __restrict__ conti, int* pc0, int* pc1, int* pc2) {
    int t = threadIdx.x;
    int st = t * 25;                                  // 256 * 25 = 6400
    int c0 = 0, c1 = 0, c2 = 0;
    for (int j = 0; j < 25; j++) {
        int w = st + j;
        if (keptC[w] > 0) {
            int l = lvl_of(cnt[w]);
            c0 += (l == 0); c1 += (l == 1); c2 += (l == 2);
        }
    }
    pc0[t] = c0; pc1[t] = c1; pc2[t] = c2;
    __syncthreads();
    if (t == 0) {
        int a = 0, b = 0, c = 0;
        for (int j = 0; j < 256; j++) {
            int v0 = pc0[j], v1 = pc1[j], v2 = pc2[j];
            pc0[j] = a; pc1[j] = b; pc2[j] = c;
            a += v0; b += v1; c += v2;
        }
    }
    __syncthreads();
    int a0 = pc0[t], a1 = pc1[t], a2 = pc2[t];
    for (int j = 0; j < 25; j++) {
        int w = st + j;
        int l = lvl_of(cnt[w]);
        conti[w] = (l == 0) ? a0 : (l == 1) ? a1 : (l == 2) ? a2 : 0;
        if (keptC[w] > 0) {
            if (l == 0) a0++; else if (l == 1) a1++; else if (l == 2) a2++;
        }
    }
}

__global__ void __launch_bounds__(256) k_fixfinal(
    int n,
    const int* __restrict__ w0a, const int* __restrict__ w1a,
    const int* __restrict__ keep0, const int* __restrict__ keepF,
    const int* __restrict__ cnt0, const int* __restrict__ cnt1,
    const int* __restrict__ keptC0, const int* __restrict__ keptC1,
    int* __restrict__ conti0, int* __restrict__ conti1,
    int* __restrict__ rk0, const int* __restrict__ rk1,
    const int* __restrict__ dropCnt, const int* __restrict__ droplist,
    const int* __restrict__ seg0,
    int* __restrict__ roleCtr, int* __restrict__ doneCtr,
    float* __restrict__ out) {
    __shared__ int roleSh;
    __shared__ int pc0[256], pc1[256], pc2[256];
    if (threadIdx.x == 0) roleSh = atomicAdd(roleCtr, 1);   // arrival-ordered
    __syncthreads();
    int role = roleSh;

    if (role < 2) {                                   // producers: conti scans
        if (role == 0) conti_scan(cnt0, keptC0, conti0, pc0, pc1, pc2);
        else           conti_scan(cnt1, keptC1, conti1, pc0, pc1, pc2);
        __syncthreads();
        if (threadIdx.x == 0)
            __hip_atomic_fetch_add(doneCtr, 1, __ATOMIC_RELEASE, __HIP_MEMORY_SCOPE_AGENT);
        return;
    }
    if (role < 2 + FIXB) {                            // producers: rk0 fixup
        int nd = *dropCnt;
        if (nd > 0) {
            int waveId = (role - 2) * 4 + (threadIdx.x >> 6);
            int lane = threadIdx.x & 63;
            for (int e = waveId; e < nd; e += FIXB * 4) {
                int u = droplist[e];
                int w = w0a[u];
                int k = cnt0[w];
                if (k <= CAP) {
                    const int* s = seg0 + w * CAP;
                    for (int j = lane; j < k; j += 64) {
                        int v = s[j];
                        if (v > u && keep0[v] && keepF[v]) atomicSub(&rk0[v], 1);
                    }
                } else if (lane == 0) {               // double-rare fallback
                    for (int i2 = u + 1; i2 < n; i2++)
                        if (w0a[i2] == w && keep0[i2] && keepF[i2]) atomicSub(&rk0[i2], 1);
                }
            }
        }
        __syncthreads();
        if (threadIdx.x == 0)
            __hip_atomic_fetch_add(doneCtr, 1, __ATOMIC_RELEASE, __HIP_MEMORY_SCOPE_AGENT);
        return;
    }

    // consumers: spin until all producers done (producers are resident by
    // construction — they claimed earlier tickets — so no deadlock)
    if (threadIdx.x == 0) {
        while (__hip_atomic_load(doneCtr, __ATOMIC_RELAXED, __HIP_MEMORY_SCOPE_AGENT) < 2 + FIXB)
            __builtin_amdgcn_s_sleep(8);
    }
    __syncthreads();
    (void)__hip_atomic_load(doneCtr, __ATOMIC_ACQUIRE, __HIP_MEMORY_SCOPE_AGENT);

    int i = (role - 2 - FIXB) * 256 + threadIdx.x;
    if (i >= n) return;
    size_t N = (size_t)n;
    float* o = out + N * 128;                         // after feat block
    int w0 = w0a[i], w1 = w1a[i];
    int k0 = keep0[i];
    int kf = (k0 && keepF[i]) ? 1 : 0;
    int l0 = lvl_of(cnt0[w0]);
    int l1 = k0 ? lvl_of(cnt1[w1]) : -1;
    int f0 = -1, f1 = -1;
    if (kf) {
        int mt0 = (l0 == 0) ? 30 : (l0 == 1) ? 60 : 100;
        int mt1 = (l1 == 0) ? 30 : (l1 == 1) ? 60 : 100;
        f0 = conti0[w0] * mt0 + rk0[i];
        f1 = conti1[w1] * mt1 + rk1[i];
    } else {
        // zero this dropped row's features (copy in A wrote them). Rare.
        f4* row = (f4*)out + (size_t)i * 32;
        f4 zz = {0.f, 0.f, 0.f, 0.f};
        for (int j = 0; j < 32; j++) row[j] = zz;
    }
    o[i]         = (float)kf;   // keep
    o[N + i]     = (float)l0;   // lvl0
    o[2 * N + i] = (float)l1;   // lvl1
    o[3 * N + i] = (float)w0;   // bwi0
    o[4 * N + i] = (float)w1;   // bwi1
    o[5 * N + i] = (float)f0;   // f2w0
    o[6 * N + i] = (float)f1;   // f2w1
}

extern "C" void kernel_launch(void* const* d_in, const int* in_sizes, int n_in,
                              void* d_out, int out_size, void* d_ws, size_t ws_size,
                              hipStream_t stream) {
    (void)n_in; (void)out_size; (void)ws_size;
    const float* feat = (const float*)d_in[0];
    const int* coors  = (const int*)d_in[1];
    int n = in_sizes[1] / 4;           // coors is [N,4]
    float* out = (float*)d_out;
    int* ws = (int*)d_ws;

    // workspace layout (ints): header + 7n + 2*NWIN*CAP ~= 15.2 MB at N=300000
    int* cnt0     = ws;                // zeroed
    int* cnt1     = ws + 6400;         // zeroed
    int* keptC0   = ws + 12800;        // zeroed
    int* dropCnt  = ws + 19200;        // zeroed
    int* roleCtr  = ws + 19201;        // zeroed
    int* doneCtr  = ws + 19202;        // zeroed
    int* keptC1   = ws + 25600;
    int* conti0   = ws + 32000;
    int* conti1   = ws + 38400;
    int* droplist = ws + 44800;        // n ints (worst case)
    int* w0a      = droplist + n;
    int* w1a      = w0a + n;
    int* keep0    = w1a + n;
    int* keepF    = keep0 + n;
    int* rk0      = keepF + n;
    int* rk1      = rk0 + n;
    int* seg0     = rk1 + n;
    int* seg1     = seg0 + NWIN * CAP;

    int nb = (n + 255) / 256;
    int fb = (n * 32 + 255) / 256;

    k_zero<<<(3 * NWIN + 3 + 255) / 256, 256, 0, stream>>>(cnt0);
    k_copyscat<<<fb + nb, 256, 0, stream>>>((const int4*)coors, n, w0a, w1a,
                                            cnt0, seg0, (const f4*)feat,
                                            (f4*)out, fb);
    k_rank0<<<NWIN / 4, 256, 0, stream>>>(cnt0, seg0, w0a, w1a, n,
                                          keep0, rk0, cnt1, seg1);
    k_rank1<<<NWIN / 4, 256, 0, stream>>>(cnt1, seg1, w0a, w1a, keep0, n,
                                          keepF, rk1, keptC1, keptC0,
                                          dropCnt, droplist);
    k_fixfinal<<<2 + FIXB + nb, 256, 0, stream>>>(n, w0a, w1a, keep0, keepF,
                                                  cnt0, cnt1, keptC0, keptC1,
                                                  conti0, conti1, rk0, rk1,
                                                  dropCnt, droplist, seg0,
                                                  roleCtr, doneCtr, out);
}

// Round 6
// 377.793 us; speedup vs baseline: 1.1716x; 1.1716x over previous
//
#include <hip/hip_runtime.h>

// SST input layer: window partition + per-window drop + flat2win re-indexing.
// Static config: WIN=12, GRID=468, BATCH=4, SHIFTS=((0,0),(6,6)), MAX_WIN_Y=40,
//   window ids in [0, 6400). DROP_INFO: cnt<30 -> lvl0,t30 ; cnt<60 -> lvl1,t60 ;
//   cnt<100000 -> lvl2,t100.
//
// Structure (6 stream-ordered dispatches — R3 structure, best verified 390us;
// R1 showed coop grid.sync ~75us/sync; R4 showed ticket-spin + copy-fusion
// regress ~+50us, both reverted). R5 bench was an infra failure (container
// acquisition), not a kernel verdict — this source is the R5 kernel resubmitted
// unchanged after a bounds/footprint audit (12.9 MB ws < R3's 15.2 MB; all
// seg writes gated by p < CAP; no spin/coop constructs).
//   K0 zero     : header (cnt0,cnt1,keptC0,dropCnt) = 0 ; rk0,rk1 = -1
//   K1 winscat  : window ids (packed int2) + scatter into fixed-CAP shift-0 segs
//   K2 rank0    : wave/window shfl rank -> rk0 (sentinel: >=0 means keep0),
//                 fused shift-1 hist+scatter
//   K3 rank1    : wave/window shfl rank -> rk1 (sentinel: >=0 means final-kept),
//                 keptC1 closed form, keptC0 atomics, droplist of dropped
//   K4 fix      : blocks 0-1: conti scans; rest: sparse rk0 decrement from
//                 droplist (statistically empty: drops need window count>100
//                 at mean 49, sigma 7)
//   K5 finalfeat: per-voxel scalar outputs + masked float4 feature copy
//
// Verified algebra (R1-R4 all passed, absmax=0):
//   * keep0 kept set is an index-prefix per shift-0 window => rank-among-keep0
//     == rank-among-all.
//   * shift-1 kept set is an index-prefix of survivors => rank-among-kept ==
//     rank, keptC1 = min(k, target).
//   * rk0 = r - #{smaller-index keep0-members dropped by shift-1} (droplist);
//     decrements never drive a kept rank below 0, so the -1 sentinel is safe.
// Sentinel encoding replaces the keep0/keepF arrays: saves ~600k scattered
// stores (rank kernels) and ~600k scattered loads (finalfeat/fix).

#define NWIN 6400
#define CAP 128    // per-window segment cap; stat max count ~80 (11 sigma)
#define HDRN (3 * NWIN + 1)   // cnt0, cnt1, keptC0, dropCnt (contiguous)

__device__ __forceinline__ int targ_of(int k) {
    return (k < 30) ? 30 : (k < 60) ? 60 : (k < 100000) ? 100 : 0;
}
__device__ __forceinline__ int lvl_of(int k) {
    return (k < 30) ? 0 : (k < 60) ? 1 : (k < 100000) ? 2 : -1;
}

// ---- K0: header = 0, rk0/rk1 = -1 ----
__global__ void k_zero(int* __restrict__ hdr, int* __restrict__ rkbuf, int n2) {
    int i = blockIdx.x * 256 + threadIdx.x;
    if (i < HDRN) hdr[i] = 0;
    if (i < n2) rkbuf[i] = -1;
}

// ---- K1: packed window ids + scatter into shift-0 segments ----
__global__ void __launch_bounds__(256) k_winscat(
    const int4* __restrict__ c4, int n, int2* __restrict__ wp,
    int* __restrict__ cnt0, int* __restrict__ seg0) {
    int i = blockIdx.x * 256 + threadIdx.x;
    if (i >= n) return;
    int4 c = c4[i];                                  // [b, z, y, x]
    int w0 = c.x * 1600 + (c.w / 12) * 40 + (c.z / 12);
    int w1 = c.x * 1600 + ((c.w + 6) / 12) * 40 + ((c.z + 6) / 12);
    int2 p2; p2.x = w0; p2.y = w1;
    wp[i] = p2;                                      // one 8B store
    int p = atomicAdd(&cnt0[w0], 1);
    if (p < CAP) seg0[w0 * CAP + p] = i;             // overflow -> serial path
}

// ---- K2: shift-0 rank -> rk0 sentinel + fused shift-1 hist+scatter ----
__global__ void __launch_bounds__(256) k_rank0(
    const int* __restrict__ cnt0, const int* __restrict__ seg0,
    const int2* __restrict__ wp, int n,
    int* __restrict__ rk0, int* __restrict__ cnt1, int* __restrict__ seg1) {
    int w = blockIdx.x * 4 + (threadIdx.x >> 6);
    int lane = threadIdx.x & 63;
    int k = cnt0[w];
    if (k == 0) return;
    int target = targ_of(k);
    const int* s = seg0 + w * CAP;
    if (k <= 64) {
        int v = (lane < k) ? s[lane] : 0x7FFFFFFF;
        int r = 0;
        for (int j = 0; j < k; j++) { int b = __shfl(v, j, 64); r += (b < v) ? 1 : 0; }
        if (lane < k && r < target) {
            rk0[v] = r;                              // rank among keep0 == r
            int w1 = wp[v].y;
            int p = atomicAdd(&cnt1[w1], 1);
            if (p < CAP) seg1[w1 * CAP + p] = v;
        }
    } else if (k <= CAP) {
        int k2 = k - 64;
        int v0 = s[lane];
        int v1 = (lane < k2) ? s[64 + lane] : 0x7FFFFFFF;
        int r0 = 0, r1 = 0;
        for (int j = 0; j < 64; j++) { int b = __shfl(v0, j, 64); r0 += (b < v0); r1 += (b < v1); }
        for (int j = 0; j < k2; j++) { int b = __shfl(v1, j, 64); r0 += (b < v0); r1 += (b < v1); }
        if (r0 < target) {
            rk0[v0] = r0;
            int w1 = wp[v0].y; int p = atomicAdd(&cnt1[w1], 1);
            if (p < CAP) seg1[w1 * CAP + p] = v0;
        }
        if (lane < k2 && r1 < target) {
            rk0[v1] = r1;
            int w1 = wp[v1].y; int p = atomicAdd(&cnt1[w1], 1);
            if (p < CAP) seg1[w1 * CAP + p] = v1;
        }
    } else {
        // correctness fallback (statistically never): serial in-order scan
        if (lane == 0) {
            int c = 0;
            for (int i = 0; i < n; i++) {
                if (wp[i].x == w) {
                    if (c < target) {
                        rk0[i] = c;
                        int w1 = wp[i].y; int p = atomicAdd(&cnt1[w1], 1);
                        if (p < CAP) seg1[w1 * CAP + p] = i;
                    }
                    c++;
                }
            }
        }
    }
}

// ---- K3: shift-1 rank -> rk1 sentinel, keptC1, keptC0 atomics, droplist ----
__global__ void __launch_bounds__(256) k_rank1(
    const int* __restrict__ cnt1, const int* __restrict__ seg1,
    const int2* __restrict__ wp, const int* __restrict__ rk0, int n,
    int* __restrict__ rk1, int* __restrict__ keptC1, int* __restrict__ keptC0,
    int* __restrict__ dropCnt, int* __restrict__ droplist) {
    int w = blockIdx.x * 4 + (threadIdx.x >> 6);
    int lane = threadIdx.x & 63;
    int k = cnt1[w];
    int target = targ_of(k);
    if (lane == 0) keptC1[w] = (k < target) ? k : target;   // prefix property
    if (k == 0) return;
    const int* s = seg1 + w * CAP;
    if (k <= 64) {
        int v = (lane < k) ? s[lane] : 0x7FFFFFFF;
        int r = 0;
        for (int j = 0; j < k; j++) { int b = __shfl(v, j, 64); r += (b < v) ? 1 : 0; }
        if (lane < k) {
            if (r < target) { rk1[v] = r; atomicAdd(&keptC0[wp[v].x], 1); }
            else            { int d = atomicAdd(dropCnt, 1); droplist[d] = v; }
        }
    } else if (k <= CAP) {
        int k2 = k - 64;
        int v0 = s[lane];
        int v1 = (lane < k2) ? s[64 + lane] : 0x7FFFFFFF;
        int r0 = 0, r1 = 0;
        for (int j = 0; j < 64; j++) { int b = __shfl(v0, j, 64); r0 += (b < v0); r1 += (b < v1); }
        for (int j = 0; j < k2; j++) { int b = __shfl(v1, j, 64); r0 += (b < v0); r1 += (b < v1); }
        if (r0 < target) { rk1[v0] = r0; atomicAdd(&keptC0[wp[v0].x], 1); }
        else             { int d = atomicAdd(dropCnt, 1); droplist[d] = v0; }
        if (lane < k2) {
            if (r1 < target) { rk1[v1] = r1; atomicAdd(&keptC0[wp[v1].x], 1); }
            else             { int d = atomicAdd(dropCnt, 1); droplist[d] = v1; }
        }
    } else {
        if (lane == 0) {
            int c = 0;
            for (int i = 0; i < n; i++) {
                if (wp[i].y == w && rk0[i] >= 0) {
                    if (c < target) { rk1[i] = c; atomicAdd(&keptC0[wp[i].x], 1); }
                    else            { int d = atomicAdd(dropCnt, 1); droplist[d] = i; }
                    c++;
                }
            }
        }
    }
}

// ---- K4: conti scans (blocks 0,1) + sparse rk0 fixup from droplist ----
__device__ __forceinline__ void conti_scan(
    const int* __restrict__ cnt, const int* __restrict__ keptC,
    int* __restrict__ conti, int* pc0, int* pc1, int* pc2) {
    int t = threadIdx.x;
    int st = t * 25;                                  // 256 * 25 = 6400
    int c0 = 0, c1 = 0, c2 = 0;
    for (int j = 0; j < 25; j++) {
        int w = st + j;
        if (keptC[w] > 0) {
            int l = lvl_of(cnt[w]);
            c0 += (l == 0); c1 += (l == 1); c2 += (l == 2);
        }
    }
    pc0[t] = c0; pc1[t] = c1; pc2[t] = c2;
    __syncthreads();
    if (t == 0) {
        int a = 0, b = 0, c = 0;
        for (int j = 0; j < 256; j++) {
            int v0 = pc0[j], v1 = pc1[j], v2 = pc2[j];
            pc0[j] = a; pc1[j] = b; pc2[j] = c;
            a += v0; b += v1; c += v2;
        }
    }
    __syncthreads();
    int a0 = pc0[t], a1 = pc1[t], a2 = pc2[t];
    for (int j = 0; j < 25; j++) {
        int w = st + j;
        int l = lvl_of(cnt[w]);
        conti[w] = (l == 0) ? a0 : (l == 1) ? a1 : (l == 2) ? a2 : 0;
        if (keptC[w] > 0) {
            if (l == 0) a0++; else if (l == 1) a1++; else if (l == 2) a2++;
        }
    }
}

__global__ void k_fix(
    const int* __restrict__ cnt0, const int* __restrict__ keptC0, int* __restrict__ conti0,
    const int* __restrict__ cnt1, const int* __restrict__ keptC1, int* __restrict__ conti1,
    const int* __restrict__ dropCnt, const int* __restrict__ droplist,
    const int2* __restrict__ wp, const int* __restrict__ seg0,
    const int* __restrict__ rk1, int* __restrict__ rk0, int n) {
    __shared__ int pc0[256], pc1[256], pc2[256];
    if (blockIdx.x == 0) { conti_scan(cnt0, keptC0, conti0, pc0, pc1, pc2); return; }
    if (blockIdx.x == 1) { conti_scan(cnt1, keptC1, conti1, pc0, pc1, pc2); return; }
    // droplist apply: one wave per dropped survivor (statistically none)
    int nd = *dropCnt;
    if (nd == 0) return;
    int waveId = (blockIdx.x - 2) * 4 + (threadIdx.x >> 6);
    int nWaves = (gridDim.x - 2) * 4;
    int lane = threadIdx.x & 63;
    for (int e = waveId; e < nd; e += nWaves) {
        int u = droplist[e];
        int w = wp[u].x;
        int k = cnt0[w];
        if (k <= CAP) {
            const int* s = seg0 + w * CAP;
            for (int j = lane; j < k; j += 64) {
                int v = s[j];
                if (v > u && rk1[v] >= 0) atomicSub(&rk0[v], 1);
            }
        } else if (lane == 0) {                       // double-rare fallback
            for (int i = u + 1; i < n; i++)
                if (wp[i].x == w && rk1[i] >= 0) atomicSub(&rk0[i], 1);
        }
    }
}

// ---- K5: per-voxel scalar outputs + masked feature copy (block-split) ----
__global__ void __launch_bounds__(256) k_finalfeat(
    int n, const int2* __restrict__ wp,
    const int* __restrict__ rk0, const int* __restrict__ rk1,
    const int* __restrict__ cnt0, const int* __restrict__ cnt1,
    const int* __restrict__ conti0, const int* __restrict__ conti1,
    const float4* __restrict__ feat, float* __restrict__ out, int nbScalar) {
    if ((int)blockIdx.x < nbScalar) {
        int i = blockIdx.x * 256 + threadIdx.x;
        if (i >= n) return;
        size_t N = (size_t)n;
        float* o = out + N * 128;                     // after feat block
        int2 ww = wp[i];                              // one 8B load
        int w0 = ww.x, w1 = ww.y;
        int r0 = rk0[i], r1 = rk1[i];
        int k0 = (r0 >= 0) ? 1 : 0;                   // sentinel: keep0
        int kf = (r1 >= 0) ? 1 : 0;                   // sentinel: final keep
        int l0 = lvl_of(cnt0[w0]);
        int l1 = k0 ? lvl_of(cnt1[w1]) : -1;
        int f0 = -1, f1 = -1;
        if (kf) {
            int mt0 = (l0 == 0) ? 30 : (l0 == 1) ? 60 : 100;
            int mt1 = (l1 == 0) ? 30 : (l1 == 1) ? 60 : 100;
            f0 = conti0[w0] * mt0 + r0;
            f1 = conti1[w1] * mt1 + r1;
        }
        o[i]         = (float)kf;   // keep
        o[N + i]     = (float)l0;   // lvl0
        o[2 * N + i] = (float)l1;   // lvl1
        o[3 * N + i] = (float)w0;   // bwi0
        o[4 * N + i] = (float)w1;   // bwi1
        o[5 * N + i] = (float)f0;   // f2w0
        o[6 * N + i] = (float)f1;   // f2w1
    } else {
        int gid = (blockIdx.x - nbScalar) * 256 + threadIdx.x;
        int total = n * 32;                           // 128 floats = 32 float4/row
        if (gid >= total) return;
        int row = gid >> 5;
        float4 v = feat[gid];
        if (rk1[row] < 0) { v.x = 0.f; v.y = 0.f; v.z = 0.f; v.w = 0.f; }
        ((float4*)out)[gid] = v;
    }
}

extern "C" void kernel_launch(void* const* d_in, const int* in_sizes, int n_in,
                              void* d_out, int out_size, void* d_ws, size_t ws_size,
                              hipStream_t stream) {
    (void)n_in; (void)out_size; (void)ws_size;
    const float* feat = (const float*)d_in[0];
    const int* coors  = (const int*)d_in[1];
    int n = in_sizes[1] / 4;           // coors is [N,4]
    float* out = (float*)d_out;
    int* ws = (int*)d_ws;

    int nAl = (n + 1) & ~1;            // even, for int2 alignment

    // workspace layout (ints): header + 5n + 2*NWIN*CAP ~= 12.9 MB at N=300000
    int* cnt0     = ws;                // \ zeroed (contiguous HDRN)
    int* cnt1     = ws + 6400;         // |
    int* keptC0   = ws + 12800;        // |
    int* dropCnt  = ws + 19200;        // /
    int* keptC1   = ws + 25600;
    int* conti0   = ws + 32000;
    int* conti1   = ws + 38400;
    int* droplist = ws + 44800;        // n ints (worst case)
    int2* wp      = (int2*)(droplist + nAl);  // 2n ints, 8B aligned
    int* rk0      = (int*)wp + 2 * nAl;       // \ contiguous 2n, set to -1
    int* rk1      = rk0 + n;                  // /
    int* seg0     = rk1 + n;
    int* seg1     = seg0 + NWIN * CAP;

    int nb = (n + 255) / 256;
    int fb = (n * 32 + 255) / 256;
    int n2 = 2 * n;
    int zmax = (n2 > HDRN) ? n2 : HDRN;

    k_zero<<<(zmax + 255) / 256, 256, 0, stream>>>(cnt0, rk0, n2);
    k_winscat<<<nb, 256, 0, stream>>>((const int4*)coors, n, wp, cnt0, seg0);
    k_rank0<<<NWIN / 4, 256, 0, stream>>>(cnt0, seg0, wp, n, rk0, cnt1, seg1);
    k_rank1<<<NWIN / 4, 256, 0, stream>>>(cnt1, seg1, wp, rk0, n,
                                          rk1, keptC1, keptC0, dropCnt, droplist);
    k_fix<<<34, 256, 0, stream>>>(cnt0, keptC0, conti0, cnt1, keptC1, conti1,
                                  dropCnt, droplist, wp, seg0, rk1, rk0, n);
    k_finalfeat<<<nb + fb, 256, 0, stream>>>(n, wp, rk0, rk1, cnt0, cnt1,
                                             conti0, conti1,
                                             (const float4*)feat, out, nb);
}